// Round 9
// baseline (382.568 us; speedup 1.0000x reference)
//
#include <hip/hip_runtime.h>
#include <hip/hip_bf16.h>

typedef __hip_bfloat16 bf16;
typedef __attribute__((ext_vector_type(8))) short s8v;   // 8 x bf16 (4 VGPRs)
typedef __attribute__((ext_vector_type(4))) short s4v;   // 4 x bf16 (2 VGPRs)
typedef __attribute__((ext_vector_type(4))) float f4v;   // MFMA accumulator

#define LOG2E 1.44269504088896340736f
#define CSCALE (0.125f * LOG2E)          // fold 1/sqrt(64) and log2e
#define MASK_B2 (-14426.950408889634f)   // -10000 * LOG2E (log2-domain bias)
#define NEG_BIG (-30000.0f)

#define BB 2
#define LL 2048
#define DD 1024
#define HH 16
#define HD 64
#define MTOT 4096
#define PER_T 4194304  // B*H*L*HD elements (8 MiB bf16)

struct alignas(8) B4 { bf16 v[4]; };

__device__ __forceinline__ void async_cp16(const bf16* g, bf16* l) {
    __builtin_amdgcn_global_load_lds(
        (const __attribute__((address_space(1))) void*)g,
        (__attribute__((address_space(3))) void*)l, 16, 0, 0);
}

// K=16 bf16 MFMA (v_mfma_f32_16x16x16_bf16, cdna4_isa.md §10). Direct call:
// __has_builtin is unusable here (false for all amdgcn builtins in the host
// pass), but direct calls compile in both passes (rounds 5-7 evidence).
__device__ __forceinline__ f4v mfma16x16x16bf(s4v a, s4v b, f4v c) {
    return __builtin_amdgcn_mfma_f32_16x16x16bf16_1k(a, b, c, 0, 0, 0);
}

// pack 2 f32 -> 2 bf16 (round-half-up) in one v_perm
__device__ __forceinline__ unsigned pk2(float lo, float hi) {
    unsigned a = __builtin_bit_cast(unsigned, hi) + 0x8000u;
    unsigned b = __builtin_bit_cast(unsigned, lo) + 0x8000u;
    return __builtin_amdgcn_perm(a, b, 0x07060302u);
}

// ---------------------------------------------------------------------------
// f32 -> bf16 bulk conversion (3 activations + 4 weights)
// ---------------------------------------------------------------------------
struct CvtArgs {
    const float* src[7];
    bf16* dst[7];
    int n[7];
};

__global__ __launch_bounds__(256) void cvt_kernel(CvtArgs args) {
    const int which = blockIdx.y;
    const float* __restrict__ src = args.src[which];
    bf16* __restrict__ dst = args.dst[which];
    const int n4 = args.n[which] >> 2;
    const int stride = gridDim.x * 256;
    for (int i = blockIdx.x * 256 + threadIdx.x; i < n4; i += stride) {
        const float4 f = ((const float4*)src)[i];
        B4 o;
        o.v[0] = __float2bfloat16(f.x);
        o.v[1] = __float2bfloat16(f.y);
        o.v[2] = __float2bfloat16(f.z);
        o.v[3] = __float2bfloat16(f.w);
        ((B4*)dst)[i] = o;
    }
}

// ---------------------------------------------------------------------------
// m97-style GEMM, MT x 128 tile, BK=64, global_load_lds + XOR swizzle.
// FUSED=1 (MT=128): grid.z selects Q/K/V; head-major stores (V transposed).
// FUSED=0 (MT=64): O-projection, f32 store gated by any(mask[b,:]).
// ---------------------------------------------------------------------------
struct QkvArgs {
    const bf16* A[3];
    const bf16* W[3];
    const float* bias[3];
    bf16* out[3];
};

template <int FUSED, int MT>
__global__ __launch_bounds__(256) void gemm128(QkvArgs qa,
                                               const bf16* __restrict__ Ao,
                                               const bf16* __restrict__ Wo_,
                                               const float* __restrict__ bo_,
                                               float* __restrict__ out_f,
                                               const int* __restrict__ mask) {
    __shared__ bf16 sA[MT * 64];
    __shared__ bf16 sB[128 * 64];
    __shared__ int sgate;
    constexpr int NI = MT / 32;

    const int which = FUSED ? blockIdx.z : 0;
    const bf16* __restrict__ A = FUSED ? qa.A[which] : Ao;
    const bf16* __restrict__ W = FUSED ? qa.W[which] : Wo_;
    const float* __restrict__ bias = FUSED ? qa.bias[which] : bo_;
    bf16* __restrict__ out_bf = FUSED ? qa.out[which] : nullptr;

    const int lane = threadIdx.x & 63;
    const int w = threadIdx.x >> 6;
    const int lr = lane & 15;
    const int quad = lane >> 4;
    const int wr = w >> 1, wc = w & 1;
    const int rbase = blockIdx.x * MT;
    const int cbase = blockIdx.y * 128;
    const int dma_r = lane >> 3;
    const int dma_cc = ((lane & 7) ^ dma_r) * 8;

    if (!FUSED) {
        if (threadIdx.x == 0) sgate = 0;
        __syncthreads();
        const int b_ = rbase >> 11;
        int any = 0;
        for (int i = threadIdx.x; i < LL; i += 256) any |= mask[b_ * LL + i];
        if (any) sgate = 1;
    }

    f4v acc[NI][4] = {};
    for (int kt = 0; kt < DD / 64; kt++) {
        const int k0 = kt * 64;
        __syncthreads();
#pragma unroll
        for (int t = 0; t < NI; t++) {   // MT/8 groups over 4 waves
            const int g = w * NI + t;
            async_cp16(A + (size_t)(rbase + g * 8 + dma_r) * DD + k0 + dma_cc,
                       &sA[g * 512]);
        }
#pragma unroll
        for (int t = 0; t < 4; t++) {
            const int g = w * 4 + t;
            async_cp16(W + (size_t)(cbase + g * 8 + dma_r) * DD + k0 + dma_cc,
                       &sB[g * 512]);
        }
        __syncthreads();
#pragma unroll
        for (int s = 0; s < 2; s++) {
            s8v a[NI], b[4];
#pragma unroll
            for (int i = 0; i < NI; i++) {
                const int row = wr * (MT / 2) + i * 16 + lr;
                a[i] = *(const s8v*)&sA[row * 64 + (((s * 4 + quad) ^ (row & 7)) * 8)];
            }
#pragma unroll
            for (int j = 0; j < 4; j++) {
                const int row = wc * 64 + j * 16 + lr;
                b[j] = *(const s8v*)&sB[row * 64 + (((s * 4 + quad) ^ (row & 7)) * 8)];
            }
#pragma unroll
            for (int i = 0; i < NI; i++)
#pragma unroll
                for (int j = 0; j < 4; j++)
                    acc[i][j] = __builtin_amdgcn_mfma_f32_16x16x32_bf16(a[i], b[j], acc[i][j], 0, 0, 0);
        }
    }

    const float gatef = (!FUSED) ? (sgate ? 1.0f : 0.0f) : 1.0f;

#pragma unroll
    for (int j = 0; j < 4; j++) {
        const int n = cbase + wc * 64 + j * 16 + lr;
        const float bv = bias[n];
#pragma unroll
        for (int i = 0; i < NI; i++) {
#pragma unroll
            for (int r = 0; r < 4; r++) {
                const int m = rbase + wr * (MT / 2) + i * 16 + quad * 4 + r;
                const float v = acc[i][j][r] + bv;
                if (!FUSED) {
                    out_f[(size_t)m * DD + n] = v * gatef;
                } else {
                    const int b_ = m >> 11, l = m & (LL - 1);
                    const int h = n >> 6, hd = n & 63;
                    if (which == 2)
                        out_bf[(((size_t)(b_ * HH + h)) * HD + hd) * LL + l] = __float2bfloat16(v);
                    else
                        out_bf[(((size_t)(b_ * HH + h)) * LL + l) * HD + hd] = __float2bfloat16(v);
                }
            }
        }
    }
}

// ---------------------------------------------------------------------------
// Flash attention, split-k-across-waves. Block = (b,h,64q); wave w owns keys
// [w*16, w*16+16) of each 64-key tile, all 64 q (Q in regs). Independent
// per-wave online softmax; C-layout of S^T == A-layout of K=16 PV (no P
// exchange). End-of-block merge: m/l exchange + LDS atomic O reduction.
// ---------------------------------------------------------------------------
__global__ __launch_bounds__(256, 3) void attn_kernel(const bf16* __restrict__ Q,
                                                      const bf16* __restrict__ K,
                                                      const bf16* __restrict__ Vt,
                                                      const int* __restrict__ mask,
                                                      bf16* __restrict__ Aout) {
    __shared__ bf16 sKV[2][2][64 * 64];     // [buf][K/V], 32 KB; reused as R
    __shared__ float sBias[LL];             // 8 KB
    __shared__ float sML[4][4][2][16];      // [grp][wave][m/l][q16], 2 KB

    const int lane = threadIdx.x & 63;
    const int w = threadIdx.x >> 6;
    const int lr = lane & 15;
    const int quad = lane >> 4;

    const int bid = blockIdx.x;
    const int qb = bid & 31;
    const int h = (bid >> 5) & 15;
    const int b = bid >> 9;

    const size_t head_off = ((size_t)(b * HH + h)) * LL * HD;
    const bf16* Qh = Q + head_off;
    const bf16* Kh = K + head_off;
    const bf16* Vh = Vt + head_off;    // [HD][LL] per head
    const int q0 = qb * 64;

    const int dma_r = lane >> 3;
    const int dma_cc = ((lane & 7) ^ dma_r) * 8;

    {   // prologue: bias fill + stage tile 0
        const int* mb = mask + b * LL;
        for (int i = threadIdx.x; i < LL; i += 256)
            sBias[i] = mb[i] ? 0.0f : MASK_B2;
#pragma unroll
        for (int t = 0; t < 2; t++) {
            const int g = w * 2 + t;
            async_cp16(Kh + (size_t)(g * 8 + dma_r) * HD + dma_cc, &sKV[0][0][g * 512]);
            async_cp16(Vh + (size_t)(g * 8 + dma_r) * LL + dma_cc, &sKV[0][1][g * 512]);
        }
    }
    __syncthreads();

    // Q fragments in registers: 4 q-groups x 2 k-chunks (B-operand layout)
    s8v Qf[4][2];
#pragma unroll
    for (int j = 0; j < 4; j++)
#pragma unroll
        for (int c = 0; c < 2; c++)
            Qf[j][c] = *(const s8v*)(Qh + (size_t)(q0 + j * 16 + lr) * HD + c * 32 + quad * 8);

    f4v O[4][4] = {};                  // [q-grp][d-grp], C: row=q, col=d
    float m[4], l[4];
#pragma unroll
    for (int j = 0; j < 4; j++) { m[j] = NEG_BIG; l[j] = 0.0f; }

    const int krow = w * 16 + lr;      // this wave's key row in the tile
    const int ksw = lr & 7;
    const int vchunkbase = w * 2 + (quad >> 1);
    const int vsub = (quad & 1) * 4;
    int asrc[4];
#pragma unroll
    for (int r = 0; r < 4; r++) asrc[r] = (lane & 48) | (quad * 4 + r);

    for (int kt = 0; kt < LL / 64; kt++) {
        const int kb = kt * 64;
        const bf16* kb_ = &sKV[kt & 1][0][0];
        const bf16* vb_ = &sKV[kt & 1][1][0];

        if (kt < LL / 64 - 1) {
            const int nb = (kt + 1) & 1;
#pragma unroll
            for (int t = 0; t < 2; t++) {
                const int g = w * 2 + t;
                async_cp16(Kh + (size_t)(kb + 64 + g * 8 + dma_r) * HD + dma_cc,
                           &sKV[nb][0][g * 512]);
                async_cp16(Vh + (size_t)(g * 8 + dma_r) * LL + kb + 64 + dma_cc,
                           &sKV[nb][1][g * 512]);
            }
        }

        // S^T = K_w Q^T : A = this wave's 16 key rows, B = Q groups
        const s8v kf0 = *(const s8v*)&kb_[krow * 64 + ((quad ^ ksw) * 8)];
        const s8v kf1 = *(const s8v*)&kb_[krow * 64 + (((4 + quad) ^ ksw) * 8)];
        f4v T[4];
#pragma unroll
        for (int j = 0; j < 4; j++) {
            f4v t = {};
            t = __builtin_amdgcn_mfma_f32_16x16x32_bf16(kf0, Qf[j][0], t, 0, 0, 0);
            T[j] = __builtin_amdgcn_mfma_f32_16x16x32_bf16(kf1, Qf[j][1], t, 0, 0, 0);
        }

        // V fragments (B-operand, K=16): row=d, cols = this wave's keys
        s4v vf[4];
#pragma unroll
        for (int dt = 0; dt < 4; dt++) {
            const int vrow = dt * 16 + lr;
            vf[dt] = *(const s4v*)&vb_[vrow * 64 + ((vchunkbase ^ (lr & 7)) * 8) + vsub];
        }

        // log2-domain scores + per-group max (k on reg axis: 3 max + 2 shuffles)
        const f4v bj = *(const f4v*)&sBias[kb + w * 16 + quad * 4];
        float mloc[4], mnew[4];
#pragma unroll
        for (int j = 0; j < 4; j++) {
#pragma unroll
            for (int r = 0; r < 4; r++) T[j][r] = T[j][r] * CSCALE + bj[r];
            float v = fmaxf(fmaxf(T[j][0], T[j][1]), fmaxf(T[j][2], T[j][3]));
            v = fmaxf(v, __shfl_xor(v, 16));
            v = fmaxf(v, __shfl_xor(v, 32));
            mloc[j] = v;
            mnew[j] = fmaxf(m[j], v);
        }

        const bool upd = (mnew[0] > m[0]) | (mnew[1] > m[1]) |
                         (mnew[2] > m[2]) | (mnew[3] > m[3]);
        if (__any(upd)) {
#pragma unroll
            for (int j = 0; j < 4; j++) {
                const float alpha = __builtin_amdgcn_exp2f(m[j] - mnew[j]);
                m[j] = mnew[j];
                l[j] *= alpha;
#pragma unroll
                for (int r = 0; r < 4; r++) {
                    const float aB = __shfl(alpha, asrc[r]);
                    O[j][0][r] *= aB; O[j][1][r] *= aB;
                    O[j][2][r] *= aB; O[j][3][r] *= aB;
                }
            }
        }

        // exp + per-group sum + P pack (A-operand == C layout, in-register)
        s4v P[4];
#pragma unroll
        for (int j = 0; j < 4; j++) {
            float e0 = __builtin_amdgcn_exp2f(T[j][0] - m[j]);
            float e1 = __builtin_amdgcn_exp2f(T[j][1] - m[j]);
            float e2 = __builtin_amdgcn_exp2f(T[j][2] - m[j]);
            float e3 = __builtin_amdgcn_exp2f(T[j][3] - m[j]);
            float ls = (e0 + e1) + (e2 + e3);
            ls += __shfl_xor(ls, 16);
            ls += __shfl_xor(ls, 32);
            l[j] += ls;
            const unsigned u01 = pk2(e0, e1);
            const unsigned u23 = pk2(e2, e3);
            int2 pi = make_int2((int)u01, (int)u23);
            P[j] = __builtin_bit_cast(s4v, pi);
        }

#pragma unroll
        for (int j = 0; j < 4; j++)
#pragma unroll
            for (int dt = 0; dt < 4; dt++)
                O[j][dt] = mfma16x16x16bf(P[j], vf[dt], O[j][dt]);

        __syncthreads();   // buffer handoff (drains next-tile DMA)
    }

    // ---- merge across waves ----
    if (lane < 16) {
#pragma unroll
        for (int j = 0; j < 4; j++) {
            sML[j][w][0][lane] = m[j];
            sML[j][w][1][lane] = l[j];
        }
    }
    float* R = (float*)&sKV[0][0][0];   // 64 x 68 f32 (17.4 KB), K/V dead now
    {
        f4v z = {};
        for (int i = threadIdx.x; i < 64 * 68 / 4; i += 256) ((f4v*)R)[i] = z;
    }
    __syncthreads();

#pragma unroll
    for (int j = 0; j < 4; j++) {
        float mg = NEG_BIG, lg = 0.0f;
        float mw[4], lw[4];
#pragma unroll
        for (int ww = 0; ww < 4; ww++) {
            mw[ww] = sML[j][ww][0][lr];
            lw[ww] = sML[j][ww][1][lr];
            mg = fmaxf(mg, mw[ww]);
        }
#pragma unroll
        for (int ww = 0; ww < 4; ww++) lg += lw[ww] * __builtin_amdgcn_exp2f(mw[ww] - mg);
        const float sc = __builtin_amdgcn_exp2f(m[j] - mg) / lg;
#pragma unroll
        for (int r = 0; r < 4; r++) {
            const float f = __shfl(sc, asrc[r]);
            const int row = j * 16 + quad * 4 + r;
#pragma unroll
            for (int dt = 0; dt < 4; dt++)
                atomicAdd(&R[row * 68 + dt * 16 + lr], O[j][dt][r] * f);
        }
    }
    __syncthreads();

    // cooperative pack + store: wave w takes q rows [w*16, w*16+16)
    {
        const int qloc = w * 16 + (lane >> 2);
        const int dbase = (lane & 3) * 16;
        bf16* dst = Aout + ((size_t)(b * LL + q0 + qloc)) * DD + h * HD + dbase;
#pragma unroll
        for (int c = 0; c < 4; c++) {
            const f4v x = *(const f4v*)&R[qloc * 68 + dbase + c * 4];
            int2 o = make_int2((int)pk2(x[0], x[1]), (int)pk2(x[2], x[3]));
            *(int2*)(dst + c * 4) = o;
        }
    }
}

// ---------------------------------------------------------------------------
extern "C" void kernel_launch(void* const* d_in, const int* in_sizes, int n_in,
                              void* d_out, int out_size, void* d_ws, size_t ws_size,
                              hipStream_t stream) {
    const float* query = (const float*)d_in[0];
    const float* key   = (const float*)d_in[1];
    const float* value = (const float*)d_in[2];
    const float* Wq = (const float*)d_in[3];
    const float* bq = (const float*)d_in[4];
    const float* Wk = (const float*)d_in[5];
    const float* bk = (const float*)d_in[6];
    const float* Wv = (const float*)d_in[7];
    const float* bv = (const float*)d_in[8];
    const float* Wo = (const float*)d_in[9];
    const float* bo = (const float*)d_in[10];
    const int* mask = (const int*)d_in[11];

    bf16* base = (bf16*)d_ws;
    bf16* qx = base;
    bf16* kx = qx + PER_T;
    bf16* vx = kx + PER_T;
    bf16* wq = vx + PER_T;
    bf16* wk = wq + DD * DD;
    bf16* wv = wk + DD * DD;
    bf16* wo = wv + DD * DD;
    bf16* Qs = wo + DD * DD;
    bf16* Ks = Qs + PER_T;
    bf16* Vst = Ks + PER_T;
    bf16* aws = Vst + PER_T;

    CvtArgs ca;
    ca.src[0] = query; ca.dst[0] = qx; ca.n[0] = PER_T;
    ca.src[1] = key;   ca.dst[1] = kx; ca.n[1] = PER_T;
    ca.src[2] = value; ca.dst[2] = vx; ca.n[2] = PER_T;
    ca.src[3] = Wq;    ca.dst[3] = wq; ca.n[3] = DD * DD;
    ca.src[4] = Wk;    ca.dst[4] = wk; ca.n[4] = DD * DD;
    ca.src[5] = Wv;    ca.dst[5] = wv; ca.n[5] = DD * DD;
    ca.src[6] = Wo;    ca.dst[6] = wo; ca.n[6] = DD * DD;
    cvt_kernel<<<dim3(1024, 7), 256, 0, stream>>>(ca);

    QkvArgs qa;
    qa.A[0] = qx; qa.W[0] = wq; qa.bias[0] = bq; qa.out[0] = Qs;
    qa.A[1] = kx; qa.W[1] = wk; qa.bias[1] = bk; qa.out[1] = Ks;
    qa.A[2] = vx; qa.W[2] = wv; qa.bias[2] = bv; qa.out[2] = Vst;

    gemm128<1, 128><<<dim3(MTOT / 128, DD / 128, 3), 256, 0, stream>>>(
        qa, nullptr, nullptr, nullptr, nullptr, nullptr);

    attn_kernel<<<BB * HH * (LL / 64), 256, 0, stream>>>(Qs, Ks, Vst, mask, aws);

    QkvArgs dummy{};
    gemm128<0, 64><<<dim3(MTOT / 64, DD / 128, 1), 256, 0, stream>>>(
        dummy, aws, wo, bo, (float*)d_out, mask);
}